// Round 1
// baseline (2351.469 us; speedup 1.0000x reference)
//
#include <hip/hip_runtime.h>

typedef _Float16 f16;
typedef f16 f16x4 __attribute__((ext_vector_type(4)));
typedef f16 f16x8 __attribute__((ext_vector_type(8)));
typedef float f32x4 __attribute__((ext_vector_type(4)));

#define DEV static __device__ __forceinline__

#define NTOK 4096
#define DDIM 2048
#define IDIM 8192
#define NEXP 8
#define MAXMT 72
#define ROWS_MAX 8208

// LDS tile: [row][32 k] f16, row stride 64B, 16B granules XOR-swizzled.
DEV int swz(int row, int kg) { return row * 64 + ((kg ^ ((row >> 1) & 3)) << 4); }

DEV float gelu_exact(float v) {
  return 0.5f * v * (1.0f + erff(v * 0.70710678118654752440f));
}

// ---------------------------------------------------------------------------
// Router GEMM: hr = x[4096,2048] @ rw1[2048,1024], fp16x2 split (3 MFMAs) for
// ~1e-6 accuracy (expert-pick flips need logit err ~8e-5).
// ---------------------------------------------------------------------------
__global__ __launch_bounds__(256, 2) void router_gemm(
    const float* __restrict__ x, const float* __restrict__ rw1,
    float* __restrict__ hr) {
  __shared__ char smem[65536];  // 2 bufs x (Ah,Al,Bh,Bl) 8KB each
  const int nt = blockIdx.x;    // 0..7
  const int mt = blockIdx.y;    // 0..31
  const int rowbase = mt * 128, nbase = nt * 128;
  const int tid = threadIdx.x;

  f32x4 acc[4][4];
#pragma unroll
  for (int m = 0; m < 4; m++)
#pragma unroll
    for (int n = 0; n < 4; n++) acc[m][n] = f32x4{0.f, 0.f, 0.f, 0.f};

  int aRow[4], aK0[4], bN[2], bKg[2];
#pragma unroll
  for (int v = 0; v < 4; ++v) {
    int f = tid + v * 256;
    aRow[v] = f >> 3;
    aK0[v] = (f & 7) << 2;
  }
#pragma unroll
  for (int v = 0; v < 2; ++v) {
    int g = tid + v * 256;
    bN[v] = g & 127;
    bKg[v] = g >> 7;  // 0..3
  }

  float4 aReg[4];
  float bRegB[2][8];

  auto issue = [&](int kk) {
#pragma unroll
    for (int v = 0; v < 4; ++v)
      aReg[v] = *(const float4*)(x + (size_t)(rowbase + aRow[v]) * DDIM + kk + aK0[v]);
#pragma unroll
    for (int v = 0; v < 2; ++v)
#pragma unroll
      for (int j = 0; j < 8; ++j)
        bRegB[v][j] = rw1[(size_t)(kk + bKg[v] * 8 + j) * 1024 + nbase + bN[v]];
  };
  auto stage = [&](int buf) {
    char* Ah = smem + buf * 32768;
    char* Al = Ah + 8192;
    char* Bh = Ah + 16384;
    char* Bl = Ah + 24576;
#pragma unroll
    for (int v = 0; v < 4; ++v) {
      float vv[4] = {aReg[v].x, aReg[v].y, aReg[v].z, aReg[v].w};
      f16x4 h4, l4;
#pragma unroll
      for (int j = 0; j < 4; ++j) {
        f16 hi = (f16)vv[j];
        h4[j] = hi;
        l4[j] = (f16)(vv[j] - (float)hi);
      }
      int ad = swz(aRow[v], aK0[v] >> 3) + ((aK0[v] & 7) << 1);
      *(f16x4*)(Ah + ad) = h4;
      *(f16x4*)(Al + ad) = l4;
    }
#pragma unroll
    for (int v = 0; v < 2; ++v) {
      f16x8 h8, l8;
#pragma unroll
      for (int j = 0; j < 8; ++j) {
        float vv = bRegB[v][j];
        f16 hi = (f16)vv;
        h8[j] = hi;
        l8[j] = (f16)(vv - (float)hi);
      }
      int bd = swz(bN[v], bKg[v]);
      *(f16x8*)(Bh + bd) = h8;
      *(f16x8*)(Bl + bd) = l8;
    }
  };

  const int wid = tid >> 6, lane = tid & 63;
  const int wr = (wid >> 1) * 64, wc = (wid & 1) * 64;
  const int fr = lane & 15, kg = lane >> 4;

  auto compute = [&](int buf) {
    const char* Ah = smem + buf * 32768;
    const char* Al = Ah + 8192;
    const char* Bh = Ah + 16384;
    const char* Bl = Ah + 24576;
    f16x8 ah[4], al[4], bh[4], bl[4];
#pragma unroll
    for (int m = 0; m < 4; m++) {
      int ad = swz(wr + m * 16 + fr, kg);
      ah[m] = *(const f16x8*)(Ah + ad);
      al[m] = *(const f16x8*)(Al + ad);
    }
#pragma unroll
    for (int n = 0; n < 4; n++) {
      int bd = swz(wc + n * 16 + fr, kg);
      bh[n] = *(const f16x8*)(Bh + bd);
      bl[n] = *(const f16x8*)(Bl + bd);
    }
#pragma unroll
    for (int m = 0; m < 4; m++)
#pragma unroll
      for (int n = 0; n < 4; n++) {
        acc[m][n] = __builtin_amdgcn_mfma_f32_16x16x32_f16(ah[m], bh[n], acc[m][n], 0, 0, 0);
        acc[m][n] = __builtin_amdgcn_mfma_f32_16x16x32_f16(ah[m], bl[n], acc[m][n], 0, 0, 0);
        acc[m][n] = __builtin_amdgcn_mfma_f32_16x16x32_f16(al[m], bh[n], acc[m][n], 0, 0, 0);
      }
  };

  issue(0);
  stage(0);
  __syncthreads();
#pragma unroll 1
  for (int kt = 0; kt < 64; ++kt) {
    int buf = kt & 1;
    if (kt < 63) issue((kt + 1) * 32);
    compute(buf);
    if (kt < 63) stage(buf ^ 1);
    __syncthreads();
  }

  const int rl = lane >> 4;
#pragma unroll
  for (int n = 0; n < 4; n++) {
    int gn = nbase + wc + n * 16 + fr;
#pragma unroll
    for (int m = 0; m < 4; m++)
#pragma unroll
      for (int r = 0; r < 4; r++) {
        int gr = rowbase + wr + m * 16 + rl * 4 + r;
        hr[(size_t)gr * 1024 + gn] = acc[m][n][r];
      }
  }
}

// ---------------------------------------------------------------------------
// Router part 2: gelu(hr) @ rw2 -> softmax -> top2 -> counts/flags
// ---------------------------------------------------------------------------
__global__ __launch_bounds__(64) void router_topk(
    const float* __restrict__ hr, const float* __restrict__ rw2,
    int* __restrict__ eidx, float* __restrict__ ewgt, int* __restrict__ pos,
    int* __restrict__ cnt, unsigned* __restrict__ act) {
  const int t = blockIdx.x;
  const int l = threadIdx.x;
  float acc[8];
#pragma unroll
  for (int e = 0; e < 8; e++) acc[e] = 0.f;
  const float* row = hr + (size_t)t * 1024;
  for (int j = l; j < 1024; j += 64) {
    float g = gelu_exact(row[j]);
    const float4* rv = (const float4*)(rw2 + j * 8);
    float4 r0 = rv[0], r1 = rv[1];
    acc[0] += g * r0.x; acc[1] += g * r0.y; acc[2] += g * r0.z; acc[3] += g * r0.w;
    acc[4] += g * r1.x; acc[5] += g * r1.y; acc[6] += g * r1.z; acc[7] += g * r1.w;
  }
#pragma unroll
  for (int e = 0; e < 8; e++) {
    float v = acc[e];
#pragma unroll
    for (int s = 32; s >= 1; s >>= 1) v += __shfl_xor(v, s);
    acc[e] = v;
  }
  if (l == 0) {
    int e0 = 0;
    float m0 = acc[0];
#pragma unroll
    for (int e = 1; e < 8; e++)
      if (acc[e] > m0) { m0 = acc[e]; e0 = e; }
    int e1 = -1;
    float m1 = -1e30f;
#pragma unroll
    for (int e = 0; e < 8; e++)
      if (e != e0 && acc[e] > m1) { m1 = acc[e]; e1 = e; }
    float sum = 0.f;
#pragma unroll
    for (int e = 0; e < 8; e++) sum += expf(acc[e] - m0);
    float g0 = 1.0f / sum;
    float g1 = expf(m1 - m0) / sum;
    eidx[2 * t] = e0;
    eidx[2 * t + 1] = e1;
    ewgt[2 * t] = g0;
    ewgt[2 * t + 1] = g1;
    pos[2 * t] = atomicAdd(&cnt[e0], 1);
    pos[2 * t + 1] = atomicAdd(&cnt[e1], 1);
    atomicOr(&act[0], 1u << e0);
    atomicOr(&act[1], 1u << e1);
  }
}

// ---------------------------------------------------------------------------
// Prefix over expert counts + scatter row lists. Single block.
// ---------------------------------------------------------------------------
__global__ __launch_bounds__(256) void prefix_scatter(
    const int* __restrict__ eidx, const int* __restrict__ pos,
    const int* __restrict__ cnt, int* __restrict__ off, int* __restrict__ toff,
    int* __restrict__ rowlist, int* __restrict__ rowtk) {
  __shared__ int soff[8];
  if (threadIdx.x == 0) {
    int o = 0, to = 0;
    for (int e = 0; e < 8; e++) {
      off[e] = o;
      soff[e] = o;
      toff[e] = to;
      rowlist[o + cnt[e]] = -1;  // synthetic zero-token row -> C_e
      o += cnt[e] + 1;
      to += (cnt[e] + 1 + 127) >> 7;
    }
    off[8] = o;
    toff[8] = to;
  }
  __syncthreads();
  for (int i = threadIdx.x; i < 2 * NTOK; i += blockDim.x) {
    int e = eidx[i];
    int r = soff[e] + pos[i];
    rowtk[i] = r;
    rowlist[r] = i >> 1;  // token
  }
}

// ---------------------------------------------------------------------------
// Grouped GEMM1: h[row] = gelu(x[tok] @ w1[e] + b1[e])  (fp16 in, fp32 acc)
// ---------------------------------------------------------------------------
__global__ __launch_bounds__(256, 2) void moe_gemm1(
    const float* __restrict__ x, const float* __restrict__ w1,
    const float* __restrict__ b1, const int* __restrict__ rowlist,
    const int* __restrict__ off, const int* __restrict__ cnt,
    const int* __restrict__ toff, f16* __restrict__ h) {
  __shared__ char smem[32768];
  const int nt = blockIdx.x;   // 0..63
  const int mtg = blockIdx.y;  // global m-tile
  if (mtg >= toff[8]) return;
  int e = 0;
#pragma unroll
  for (int i = 0; i < 7; ++i) e += (mtg >= toff[i + 1]) ? 1 : 0;
  const int rowbase = off[e] + (mtg - toff[e]) * 128;
  const int segEnd = off[e] + cnt[e] + 1;
  const int nbase = nt * 128;
  const float* __restrict__ W = w1 + (size_t)e * (DDIM * (size_t)IDIM);
  const int tid = threadIdx.x;

  f32x4 acc[4][4];
#pragma unroll
  for (int m = 0; m < 4; m++)
#pragma unroll
    for (int n = 0; n < 4; n++) acc[m][n] = f32x4{0.f, 0.f, 0.f, 0.f};

  int aRow[4], aK0[4], tokv[4], bN[2], bKg[2];
#pragma unroll
  for (int v = 0; v < 4; ++v) {
    int f = tid + v * 256;
    aRow[v] = f >> 3;
    aK0[v] = (f & 7) << 2;
    int gr = rowbase + aRow[v];
    tokv[v] = (gr < segEnd) ? rowlist[gr] : -1;
  }
#pragma unroll
  for (int v = 0; v < 2; ++v) {
    int g = tid + v * 256;
    bN[v] = g & 127;
    bKg[v] = g >> 7;
  }

  float4 aReg[4];
  float bRegB[2][8];

  auto issue = [&](int kk) {
#pragma unroll
    for (int v = 0; v < 4; ++v) {
      if (tokv[v] >= 0)
        aReg[v] = *(const float4*)(x + (size_t)tokv[v] * DDIM + kk + aK0[v]);
      else
        aReg[v] = make_float4(0.f, 0.f, 0.f, 0.f);
    }
#pragma unroll
    for (int v = 0; v < 2; ++v)
#pragma unroll
      for (int j = 0; j < 8; ++j)
        bRegB[v][j] = W[(size_t)(kk + bKg[v] * 8 + j) * IDIM + nbase + bN[v]];
  };
  auto stage = [&](int buf) {
    char* A = smem + buf * 16384;
    char* B = A + 8192;
#pragma unroll
    for (int v = 0; v < 4; ++v) {
      f16x4 a4 = {(f16)aReg[v].x, (f16)aReg[v].y, (f16)aReg[v].z, (f16)aReg[v].w};
      *(f16x4*)(A + swz(aRow[v], aK0[v] >> 3) + ((aK0[v] & 7) << 1)) = a4;
    }
#pragma unroll
    for (int v = 0; v < 2; ++v) {
      f16x8 b8;
#pragma unroll
      for (int j = 0; j < 8; ++j) b8[j] = (f16)bRegB[v][j];
      *(f16x8*)(B + swz(bN[v], bKg[v])) = b8;
    }
  };

  const int wid = tid >> 6, lane = tid & 63;
  const int wr = (wid >> 1) * 64, wc = (wid & 1) * 64;
  const int fr = lane & 15, kg = lane >> 4;

  auto compute = [&](int buf) {
    const char* A = smem + buf * 16384;
    const char* B = A + 8192;
    f16x8 af[4], bf[4];
#pragma unroll
    for (int m = 0; m < 4; m++) af[m] = *(const f16x8*)(A + swz(wr + m * 16 + fr, kg));
#pragma unroll
    for (int n = 0; n < 4; n++) bf[n] = *(const f16x8*)(B + swz(wc + n * 16 + fr, kg));
#pragma unroll
    for (int m = 0; m < 4; m++)
#pragma unroll
      for (int n = 0; n < 4; n++)
        acc[m][n] = __builtin_amdgcn_mfma_f32_16x16x32_f16(af[m], bf[n], acc[m][n], 0, 0, 0);
  };

  issue(0);
  stage(0);
  __syncthreads();
#pragma unroll 1
  for (int kt = 0; kt < 64; ++kt) {
    int buf = kt & 1;
    if (kt < 63) issue((kt + 1) * 32);
    compute(buf);
    if (kt < 63) stage(buf ^ 1);
    __syncthreads();
  }

  const int rl = lane >> 4;
#pragma unroll
  for (int n = 0; n < 4; n++) {
    int gn = nbase + wc + n * 16 + fr;
    float bias = b1[e * IDIM + gn];
#pragma unroll
    for (int m = 0; m < 4; m++)
#pragma unroll
      for (int r = 0; r < 4; r++) {
        int gr = rowbase + wr + m * 16 + rl * 4 + r;
        if (gr < segEnd) {
          float v = acc[m][n][r] + bias;
          h[(size_t)gr * IDIM + gn] = (f16)gelu_exact(v);
        }
      }
  }
}

// ---------------------------------------------------------------------------
// Grouped GEMM2: Y[row] = h[row] @ w2[e] + b2[e]
// ---------------------------------------------------------------------------
__global__ __launch_bounds__(256, 2) void moe_gemm2(
    const f16* __restrict__ h, const float* __restrict__ w2,
    const float* __restrict__ b2, const int* __restrict__ off,
    const int* __restrict__ cnt, const int* __restrict__ toff,
    float* __restrict__ Y) {
  __shared__ char smem[32768];
  const int nt = blockIdx.x;   // 0..15
  const int mtg = blockIdx.y;
  if (mtg >= toff[8]) return;
  int e = 0;
#pragma unroll
  for (int i = 0; i < 7; ++i) e += (mtg >= toff[i + 1]) ? 1 : 0;
  const int rowbase = off[e] + (mtg - toff[e]) * 128;
  const int segEnd = off[e] + cnt[e] + 1;
  const int nbase = nt * 128;
  const float* __restrict__ W = w2 + (size_t)e * ((size_t)IDIM * DDIM);
  const int tid = threadIdx.x;

  f32x4 acc[4][4];
#pragma unroll
  for (int m = 0; m < 4; m++)
#pragma unroll
    for (int n = 0; n < 4; n++) acc[m][n] = f32x4{0.f, 0.f, 0.f, 0.f};

  int aRow[2], aKg[2], bN[2], bKg[2];
  bool aVal[2];
#pragma unroll
  for (int v = 0; v < 2; ++v) {
    int f = tid + v * 256;
    aRow[v] = f >> 2;
    aKg[v] = f & 3;
    aVal[v] = (rowbase + aRow[v]) < segEnd;
    int g = tid + v * 256;
    bN[v] = g & 127;
    bKg[v] = g >> 7;
  }

  f16x8 aReg[2];
  float bRegB[2][8];
  f16x8 zf;
#pragma unroll
  for (int j = 0; j < 8; ++j) zf[j] = (f16)0.f;

  auto issue = [&](int kk) {
#pragma unroll
    for (int v = 0; v < 2; ++v) {
      if (aVal[v])
        aReg[v] = *(const f16x8*)(h + (size_t)(rowbase + aRow[v]) * IDIM + kk + aKg[v] * 8);
      else
        aReg[v] = zf;
    }
#pragma unroll
    for (int v = 0; v < 2; ++v)
#pragma unroll
      for (int j = 0; j < 8; ++j)
        bRegB[v][j] = W[(size_t)(kk + bKg[v] * 8 + j) * DDIM + nbase + bN[v]];
  };
  auto stage = [&](int buf) {
    char* A = smem + buf * 16384;
    char* B = A + 8192;
#pragma unroll
    for (int v = 0; v < 2; ++v) *(f16x8*)(A + swz(aRow[v], aKg[v])) = aReg[v];
#pragma unroll
    for (int v = 0; v < 2; ++v) {
      f16x8 b8;
#pragma unroll
      for (int j = 0; j < 8; ++j) b8[j] = (f16)bRegB[v][j];
      *(f16x8*)(B + swz(bN[v], bKg[v])) = b8;
    }
  };

  const int wid = tid >> 6, lane = tid & 63;
  const int wr = (wid >> 1) * 64, wc = (wid & 1) * 64;
  const int fr = lane & 15, kg = lane >> 4;

  auto compute = [&](int buf) {
    const char* A = smem + buf * 16384;
    const char* B = A + 8192;
    f16x8 af[4], bf[4];
#pragma unroll
    for (int m = 0; m < 4; m++) af[m] = *(const f16x8*)(A + swz(wr + m * 16 + fr, kg));
#pragma unroll
    for (int n = 0; n < 4; n++) bf[n] = *(const f16x8*)(B + swz(wc + n * 16 + fr, kg));
#pragma unroll
    for (int m = 0; m < 4; m++)
#pragma unroll
      for (int n = 0; n < 4; n++)
        acc[m][n] = __builtin_amdgcn_mfma_f32_16x16x32_f16(af[m], bf[n], acc[m][n], 0, 0, 0);
  };

  issue(0);
  stage(0);
  __syncthreads();
#pragma unroll 1
  for (int kt = 0; kt < 256; ++kt) {
    int buf = kt & 1;
    if (kt < 255) issue((kt + 1) * 32);
    compute(buf);
    if (kt < 255) stage(buf ^ 1);
    __syncthreads();
  }

  const int rl = lane >> 4;
#pragma unroll
  for (int n = 0; n < 4; n++) {
    int gn = nbase + wc + n * 16 + fr;
    float bias = b2[e * DDIM + gn];
#pragma unroll
    for (int m = 0; m < 4; m++)
#pragma unroll
      for (int r = 0; r < 4; r++) {
        int gr = rowbase + wr + m * 16 + rl * 4 + r;
        if (gr < segEnd) Y[(size_t)gr * DDIM + gn] = acc[m][n][r] + bias;
      }
  }
}

// ---------------------------------------------------------------------------
// S_k = sum over active experts (slot k) of C_e
// ---------------------------------------------------------------------------
__global__ __launch_bounds__(256) void compute_S(
    const float* __restrict__ Y, const int* __restrict__ off,
    const int* __restrict__ cnt, const unsigned* __restrict__ act,
    float* __restrict__ S) {
  int d = blockIdx.x * 256 + threadIdx.x;
  if (d >= DDIM) return;
#pragma unroll
  for (int k = 0; k < 2; k++) {
    unsigned a = act[k];
    float s = 0.f;
#pragma unroll
    for (int e = 0; e < 8; e++)
      if ((a >> e) & 1) s += Y[(size_t)(off[e] + cnt[e]) * DDIM + d];
    S[k * DDIM + d] = s;
  }
}

// ---------------------------------------------------------------------------
// Combine: out[t] = sum_k w_k * (Y_row(t,k) - C_{e_k} + S_k)
// ---------------------------------------------------------------------------
__global__ __launch_bounds__(256) void combine(
    const float* __restrict__ Y, const float* __restrict__ S,
    const int* __restrict__ eidx, const float* __restrict__ ewgt,
    const int* __restrict__ rowtk, const int* __restrict__ off,
    const int* __restrict__ cnt, float* __restrict__ out) {
  const int t = blockIdx.x;
  const int e0 = eidx[2 * t], e1 = eidx[2 * t + 1];
  const float g0 = ewgt[2 * t], g1 = ewgt[2 * t + 1];
  const int r0 = rowtk[2 * t], r1 = rowtk[2 * t + 1];
  const int c0 = off[e0] + cnt[e0], c1 = off[e1] + cnt[e1];
  const float4* y0 = (const float4*)(Y + (size_t)r0 * DDIM);
  const float4* y1 = (const float4*)(Y + (size_t)r1 * DDIM);
  const float4* p0 = (const float4*)(Y + (size_t)c0 * DDIM);
  const float4* p1 = (const float4*)(Y + (size_t)c1 * DDIM);
  const float4* s0 = (const float4*)(S);
  const float4* s1 = (const float4*)(S + DDIM);
  float4* o = (float4*)(out + (size_t)t * DDIM);
  for (int i = threadIdx.x; i < DDIM / 4; i += 256) {
    float4 a = y0[i], b = y1[i], ca = p0[i], cb = p1[i], sa = s0[i], sb = s1[i];
    float4 r;
    r.x = g0 * (a.x - ca.x + sa.x) + g1 * (b.x - cb.x + sb.x);
    r.y = g0 * (a.y - ca.y + sa.y) + g1 * (b.y - cb.y + sb.y);
    r.z = g0 * (a.z - ca.z + sa.z) + g1 * (b.z - cb.z + sb.z);
    r.w = g0 * (a.w - ca.w + sa.w) + g1 * (b.w - cb.w + sb.w);
    o[i] = r;
  }
}

// ---------------------------------------------------------------------------
extern "C" void kernel_launch(void* const* d_in, const int* in_sizes, int n_in,
                              void* d_out, int out_size, void* d_ws,
                              size_t ws_size, hipStream_t stream) {
  const float* x = (const float*)d_in[0];
  const float* rw1 = (const float*)d_in[1];
  const float* rw2 = (const float*)d_in[2];
  const float* w1 = (const float*)d_in[3];
  const float* b1 = (const float*)d_in[4];
  const float* w2 = (const float*)d_in[5];
  const float* b2 = (const float*)d_in[6];
  float* out = (float*)d_out;
  char* ws = (char*)d_ws;

  constexpr size_t O_CNT = 0;
  constexpr size_t O_OFF = 256;
  constexpr size_t O_TOFF = 512;
  constexpr size_t O_ACT = 768;
  constexpr size_t O_EIDX = 1024;
  constexpr size_t O_POS = O_EIDX + 4ull * 2 * NTOK;
  constexpr size_t O_EWGT = O_POS + 4ull * 2 * NTOK;
  constexpr size_t O_RTK = O_EWGT + 4ull * 2 * NTOK;
  constexpr size_t O_RL = O_RTK + 4ull * 2 * NTOK;
  constexpr size_t O_S = (O_RL + 4ull * ROWS_MAX + 255) & ~(size_t)255;
  constexpr size_t O_HR = (O_S + 4ull * 2 * DDIM + 255) & ~(size_t)255;
  constexpr size_t O_H = O_HR + 4ull * NTOK * 1024;
  constexpr size_t O_Y = O_H + 2ull * ROWS_MAX * IDIM;
  constexpr size_t WS_NEED = O_Y + 4ull * ROWS_MAX * DDIM;  // ~218.7 MB

  if (ws_size < WS_NEED) return;  // would fail validation loudly

  int* cnt = (int*)(ws + O_CNT);
  int* off = (int*)(ws + O_OFF);
  int* toff = (int*)(ws + O_TOFF);
  unsigned* act = (unsigned*)(ws + O_ACT);
  int* eidx = (int*)(ws + O_EIDX);
  int* pos = (int*)(ws + O_POS);
  float* ewgt = (float*)(ws + O_EWGT);
  int* rowtk = (int*)(ws + O_RTK);
  int* rowlist = (int*)(ws + O_RL);
  float* S = (float*)(ws + O_S);
  float* hr = (float*)(ws + O_HR);
  f16* h = (f16*)(ws + O_H);
  float* Y = (float*)(ws + O_Y);

  hipMemsetAsync(ws, 0, 1024, stream);  // cnt/off/toff/act

  router_gemm<<<dim3(8, 32), 256, 0, stream>>>(x, rw1, hr);
  router_topk<<<NTOK, 64, 0, stream>>>(hr, rw2, eidx, ewgt, pos, cnt, act);
  prefix_scatter<<<1, 256, 0, stream>>>(eidx, pos, cnt, off, toff, rowlist, rowtk);
  moe_gemm1<<<dim3(64, MAXMT), 256, 0, stream>>>(x, w1, b1, rowlist, off, cnt, toff, h);
  moe_gemm2<<<dim3(16, MAXMT), 256, 0, stream>>>(h, w2, b2, off, cnt, toff, Y);
  compute_S<<<8, 256, 0, stream>>>(Y, off, cnt, act, S);
  combine<<<NTOK, 256, 0, stream>>>(Y, S, eidx, ewgt, rowtk, off, cnt, out);
}